// Round 1
// baseline (158.244 us; speedup 1.0000x reference)
//
#include <hip/hip_runtime.h>

#define THRESHOLD 0.5f

// out[i] = (f[i] > 0.5) ? 0 : f[i]
// Derivation: in the reference, win = (max(excl_max, f) < f) which is
// vacuously false elementwise, so the GEMM/sigmoid/top-2 chain is dead code.
__global__ __launch_bounds__(256) void competitive_sparse_kernel(
    const float4* __restrict__ f, float4* __restrict__ out, int n4) {
    int i = blockIdx.x * blockDim.x + threadIdx.x;
    if (i < n4) {
        float4 v = f[i];
        float4 r;
        r.x = (v.x > THRESHOLD) ? 0.0f : v.x;
        r.y = (v.y > THRESHOLD) ? 0.0f : v.y;
        r.z = (v.z > THRESHOLD) ? 0.0f : v.z;
        r.w = (v.w > THRESHOLD) ? 0.0f : v.w;
        out[i] = r;
    }
}

extern "C" void kernel_launch(void* const* d_in, const int* in_sizes, int n_in,
                              void* d_out, int out_size, void* d_ws, size_t ws_size,
                              hipStream_t stream) {
    const float4* features = (const float4*)d_in[0];
    float4* out = (float4*)d_out;
    int n = in_sizes[0];          // 4096*4096 = 16777216, divisible by 4
    int n4 = n / 4;               // 4194304
    int block = 256;
    int grid = (n4 + block - 1) / block;  // 16384
    competitive_sparse_kernel<<<grid, block, 0, stream>>>(features, out, n4);
}